// Round 1
// baseline (12233.113 us; speedup 1.0000x reference)
//
#include <hip/hip_runtime.h>

// ---------------------------------------------------------------------------
// GRU decoder w/ attention, persistent-kernel implementation.
// Grid = 256 blocks x 256 threads, all co-resident; custom device-scope
// grid barrier between dependent phases. f32 everywhere (round 1: correctness).
// ---------------------------------------------------------------------------

#define NBLK 256
#define NTHR 256

// ---- workspace layout (float offsets) ----
#define OFF_EGI     16                         // [t*64+b][1536] emb part of gi0 (+b_ih0)
#define SZ_EGI      (32*64*1536)
#define OFF_EREAD   (OFF_EGI + SZ_EGI)         // [t*64+b][512] emb part of readout (+b_read)
#define SZ_EREAD    (32*64*512)
#define OFF_ATTPRE  (OFF_EREAD + SZ_EREAD)     // [b*128+s][512] attention precompute (+b_pre)
#define SZ_ATTPRE   (64*128*512)
#define OFF_WTQ     (OFF_ATTPRE + SZ_ATTPRE)   // W_q transposed [k][a]
#define SZ_WTQ      (512*512)
#define OFF_GI      (OFF_WTQ + SZ_WTQ)         // 2 partials [b][1536]
#define OFF_GH      (OFF_GI  + 2*98304)
#define OFF_GH1     (OFF_GH  + 2*98304)
#define OFF_GI1     (OFF_GH1 + 2*98304)        // 4 partials
#define OFF_RO      (OFF_GI1 + 4*98304)        // 4 partials [b][512]
#define OFF_H0      (OFF_RO  + 4*32768)        // double buffered [2][b][512]
#define OFF_H1      (OFF_H0  + 2*32768)
#define OFF_CTX     (OFF_H1  + 2*32768)

// ---- output layout (float offsets into d_out) ----
#define OO_G    0            // g_outputs [32][64][256]
#define OO_C    524288       // c_outputs [32][64][128]
#define OO_CP   786432       // copy_gates [32][64][1]
#define OO_HID  788480       // hidden_f [2][64][512]
#define OO_AL   854016       // attn_last [64][128]
#define OO_CTXF 862208       // cur_ctx_f [64][512]

__device__ __forceinline__ float sigm(float x) {
    x = fminf(fmaxf(x, -30.f), 30.f);
    return 1.0f / (1.0f + __expf(-x));
}
__device__ __forceinline__ float tanh_(float x) {
    x = fminf(fmaxf(x, -15.f), 15.f);
    float e = __expf(-2.0f * x);
    return (1.0f - e) / (1.0f + e);
}

// Grid barrier: monotonic counter (never reset -> no reuse race).
// release fence publishes this XCD's L2 writes; acquire fence invalidates
// stale lines before consuming other blocks' data (cross-XCD coherence).
__device__ __forceinline__ void gbar(unsigned* cnt, unsigned* gen, unsigned& g) {
    __syncthreads();
    if (threadIdx.x == 0) {
        __builtin_amdgcn_fence(__ATOMIC_RELEASE, "agent");
        unsigned v = __hip_atomic_fetch_add(cnt, 1u, __ATOMIC_RELAXED, __HIP_MEMORY_SCOPE_AGENT);
        if (v == (g + 1u) * (unsigned)NBLK - 1u) {
            __hip_atomic_fetch_add(gen, 1u, __ATOMIC_RELAXED, __HIP_MEMORY_SCOPE_AGENT);
        } else {
            while (__hip_atomic_load(gen, __ATOMIC_RELAXED, __HIP_MEMORY_SCOPE_AGENT) < g + 1u) {
                __builtin_amdgcn_s_sleep(1);
            }
        }
        __builtin_amdgcn_fence(__ATOMIC_ACQUIRE, "agent");
    }
    g += 1u;
    __syncthreads();
}

// Tiled GEMM: OUT[64 x 64tile] (+=addp) = X[64 x K] @ W[j][k]^T, K in 64-wide
// tiles [kt0, kt0+nkt). xrow/wrow are THIS thread's staging row pointers
// (row = tid>>2). LDS tiles are stored transposed ([k][row]) so the inner
// loop reads are conflict-free/broadcast.
__device__ __forceinline__ void gemm64(
    const float* __restrict__ xrow, const float* __restrict__ wrow,
    int kt0, int nkt, float* lds_x, float* lds_w,
    float* __restrict__ outp, int JW, int orow0, int j0,
    const float* __restrict__ addp, int addmode, int addJW)
{
    const int tid = threadIdx.x;
    const int tb4 = tid >> 4, tj4 = tid & 15;
    float acc[4][4];
#pragma unroll
    for (int a = 0; a < 4; ++a)
#pragma unroll
        for (int b = 0; b < 4; ++b) acc[a][b] = 0.f;

    for (int kt = kt0; kt < kt0 + nkt; ++kt) {
        const int kb = kt << 6;
        __syncthreads();
        {
            const int rl = tid >> 2;
#pragma unroll
            for (int i = 0; i < 4; ++i) {
                const int kk = ((tid & 3) << 4) + (i << 2);
                float4 xv = *(const float4*)(xrow + kb + kk);
                float4 wv = *(const float4*)(wrow + kb + kk);
                lds_x[(kk + 0) * 64 + rl] = xv.x;
                lds_x[(kk + 1) * 64 + rl] = xv.y;
                lds_x[(kk + 2) * 64 + rl] = xv.z;
                lds_x[(kk + 3) * 64 + rl] = xv.w;
                lds_w[(kk + 0) * 64 + rl] = wv.x;
                lds_w[(kk + 1) * 64 + rl] = wv.y;
                lds_w[(kk + 2) * 64 + rl] = wv.z;
                lds_w[(kk + 3) * 64 + rl] = wv.w;
            }
        }
        __syncthreads();
#pragma unroll 4
        for (int kk = 0; kk < 64; ++kk) {
            float4 xv = *(const float4*)(lds_x + kk * 64 + tb4 * 4);
            float4 wv = *(const float4*)(lds_w + kk * 64 + tj4 * 4);
            acc[0][0] += xv.x * wv.x; acc[0][1] += xv.x * wv.y;
            acc[0][2] += xv.x * wv.z; acc[0][3] += xv.x * wv.w;
            acc[1][0] += xv.y * wv.x; acc[1][1] += xv.y * wv.y;
            acc[1][2] += xv.y * wv.z; acc[1][3] += xv.y * wv.w;
            acc[2][0] += xv.z * wv.x; acc[2][1] += xv.z * wv.y;
            acc[2][2] += xv.z * wv.z; acc[2][3] += xv.z * wv.w;
            acc[3][0] += xv.w * wv.x; acc[3][1] += xv.w * wv.y;
            acc[3][2] += xv.w * wv.z; acc[3][3] += xv.w * wv.w;
        }
    }
#pragma unroll
    for (int ib = 0; ib < 4; ++ib) {
        const int row = tb4 * 4 + ib;
        const int jc = j0 + tj4 * 4;
        float4 r;
        r.x = acc[ib][0]; r.y = acc[ib][1]; r.z = acc[ib][2]; r.w = acc[ib][3];
        if (addmode == 1) {
            float4 bv = *(const float4*)(addp + jc);
            r.x += bv.x; r.y += bv.y; r.z += bv.z; r.w += bv.w;
        } else if (addmode == 2) {
            float4 bv = *(const float4*)(addp + (size_t)(orow0 + row) * addJW + jc);
            r.x += bv.x; r.y += bv.y; r.z += bv.z; r.w += bv.w;
        }
        *(float4*)(outp + (size_t)(orow0 + row) * JW + jc) = r;
    }
}

__global__ __launch_bounds__(NTHR)
void decoder_kernel(const int* __restrict__ inp, const float* __restrict__ hid,
                    const float* __restrict__ ctxin, const float* __restrict__ maskp,
                    const float* __restrict__ init_att, const float* __restrict__ embW,
                    const float* __restrict__ W_ih0, const float* __restrict__ b_ih0,
                    const float* __restrict__ W_hh0, const float* __restrict__ b_hh0,
                    const float* __restrict__ W_ih1, const float* __restrict__ b_ih1,
                    const float* __restrict__ W_hh1, const float* __restrict__ b_hh1,
                    const float* __restrict__ W_pre, const float* __restrict__ b_pre,
                    const float* __restrict__ W_q, const float* __restrict__ w_v,
                    const float* __restrict__ W_copy, const float* __restrict__ b_copy,
                    const float* __restrict__ W_read, const float* __restrict__ b_read,
                    float* __restrict__ dout, float* wsf)
{
    __shared__ float lds_x[4096];
    __shared__ float lds_w[4096];
    unsigned* cnt = (unsigned*)wsf;
    unsigned* gen = cnt + 1;
    unsigned g = 0;
    const int blk = blockIdx.x;
    const int tid = threadIdx.x;
    const int rl = tid >> 2;

    // ===================== UPFRONT =====================
    // Egi[t,b,:]   = emb_t @ W_ih0[:, :512]^T + b_ih0
    // Eread[t,b,:] = emb_t @ W_read[:, :512]^T + b_read
    // attpre[b,s,:]= ctx_bse @ W_pre^T + b_pre
    for (int jid = blk; jid < 2048; jid += NBLK) {
        if (jid < 768) {
            const int mt = jid / 24, jt = jid % 24, j0 = jt << 6;
            const int idx = inp[mt * 64 + rl];
            gemm64(embW + (size_t)idx * 512,
                   W_ih0 + (size_t)(j0 + rl) * 1024,
                   0, 8, lds_x, lds_w,
                   wsf + OFF_EGI, 1536, mt << 6, j0, b_ih0, 1, 0);
        } else if (jid < 1024) {
            const int r = jid - 768, mt = r >> 3, jt = r & 7, j0 = jt << 6;
            const int idx = inp[mt * 64 + rl];
            gemm64(embW + (size_t)idx * 512,
                   W_read + (size_t)(j0 + rl) * 1536,
                   0, 8, lds_x, lds_w,
                   wsf + OFF_EREAD, 512, mt << 6, j0, b_read, 1, 0);
        } else {
            const int r = jid - 1024, mt = r >> 3, jt = r & 7, j0 = jt << 6;
            const int m = (mt << 6) + rl, b = m >> 7, s = m & 127;
            gemm64(ctxin + (size_t)((s << 6) + b) * 512,
                   W_pre + (size_t)(j0 + rl) * 512,
                   0, 8, lds_x, lds_w,
                   wsf + OFF_ATTPRE, 512, mt << 6, j0, b_pre, 1, 0);
        }
    }
    // state init (prev buffers = index 1, since t=0 has cur=0) + W_q transpose
    if (blk == 0) {
        for (int i = 0; i < 128; ++i) { int e = i * 256 + tid; wsf[OFF_H0 + 32768 + e] = hid[e]; }
    } else if (blk == 1) {
        for (int i = 0; i < 128; ++i) { int e = i * 256 + tid; wsf[OFF_H1 + 32768 + e] = hid[32768 + e]; }
    } else if (blk == 2) {
        for (int i = 0; i < 128; ++i) { int e = i * 256 + tid; wsf[OFF_CTX + 32768 + e] = init_att[e]; }
    } else if (blk >= 3 && blk < 11) {
        const int base = (blk - 3) * 32768;
        for (int i = 0; i < 128; ++i) {
            int e = base + i * 256 + tid;
            int a = e >> 9, k = e & 511;
            wsf[OFF_WTQ + k * 512 + a] = W_q[a * 512 + k];
        }
    }
    gbar(cnt, gen, g);

    // ===================== TIME LOOP =====================
    for (int t = 0; t < 32; ++t) {
        const int cur = t & 1, prv = cur ^ 1;
        float* h0_cur = wsf + OFF_H0 + cur * 32768;
        const float* h0_prv = wsf + OFF_H0 + prv * 32768;
        float* h1_cur = wsf + OFF_H1 + cur * 32768;
        const float* h1_prv = wsf + OFF_H1 + prv * 32768;
        float* ctx_cur = wsf + OFF_CTX + cur * 32768;
        const float* ctx_prv = wsf + OFF_CTX + prv * 32768;

        // ---- Phase A: GI (ctx part of gi0), GH (gh0), GH1 (gh1) ----
        if (blk < 144) {
            const int m = blk / 48, r = blk % 48, jt = r >> 1, kh = r & 1, j0 = jt << 6;
            const float* X; const float* W; int wstride, woff;
            float* outp; const float* addp; int addmode;
            if (m == 0) {
                X = ctx_prv; W = W_ih0; wstride = 1024; woff = 512;
                outp = wsf + OFF_GI + kh * 98304;
                addmode = kh ? 0 : 2; addp = wsf + OFF_EGI + (size_t)t * 98304;
            } else if (m == 1) {
                X = h0_prv; W = W_hh0; wstride = 512; woff = 0;
                outp = wsf + OFF_GH + kh * 98304;
                addmode = kh ? 0 : 1; addp = b_hh0;
            } else {
                X = h1_prv; W = W_hh1; wstride = 512; woff = 0;
                outp = wsf + OFF_GH1 + kh * 98304;
                addmode = kh ? 0 : 1; addp = b_hh1;
            }
            gemm64(X + rl * 512, W + (size_t)(j0 + rl) * wstride + woff,
                   kh * 4, 4, lds_x, lds_w, outp, 1536, 0, j0, addp, addmode, 1536);
        }
        gbar(cnt, gen, g);

        // ---- Phase B: combine h0 (blocks 0-31); readout GEMM for t-1 (32-63) ----
        if (blk < 32) {
            const float* GIp = wsf + OFF_GI;
            const float* GHp = wsf + OFF_GH;
#pragma unroll
            for (int i = 0; i < 4; ++i) {
                const int e = (blk << 10) + (i << 8) + tid;
                const int b = e >> 9, c = e & 511;
                const int base = b * 1536 + c;
                float gr = GIp[base]        + GIp[98304 + base];
                float gz = GIp[base + 512]  + GIp[98304 + base + 512];
                float gn = GIp[base + 1024] + GIp[98304 + base + 1024];
                float hr = GHp[base]        + GHp[98304 + base];
                float hz = GHp[base + 512]  + GHp[98304 + base + 512];
                float hn = GHp[base + 1024] + GHp[98304 + base + 1024];
                float rr = sigm(gr + hr);
                float zz = sigm(gz + hz);
                float nn = tanh_(gn + rr * hn);
                h0_cur[b * 512 + c] = (1.f - zz) * nn + zz * h0_prv[b * 512 + c];
            }
        } else if (blk < 64) {
            if (t > 0) {
                const int r = blk - 32, mat = r >> 4, kh = (r >> 3) & 1, jt = r & 7, j0 = jt << 6;
                const float* X = mat ? ctx_prv : h1_prv;
                gemm64(X + rl * 512,
                       W_read + (size_t)(j0 + rl) * 1536 + 512 + mat * 512,
                       kh * 4, 4, lds_x, lds_w,
                       wsf + OFF_RO + (mat * 2 + kh) * 32768, 512, 0, j0, nullptr, 0, 0);
            }
        }
        gbar(cnt, gen, g);

        // ---- Phase C: gi1 GEMM (0-95); maxout for t-1 (96-103) ----
        if (blk < 96) {
            const int jt = blk >> 2, kq = blk & 3, j0 = jt << 6;
            gemm64(h0_cur + rl * 512, W_ih1 + (size_t)(j0 + rl) * 512,
                   kq * 2, 2, lds_x, lds_w,
                   wsf + OFF_GI1 + kq * 98304, 1536, 0, j0,
                   b_ih1, kq == 0 ? 1 : 0, 0);
        } else if (blk < 104) {
            if (t > 0) {
                const int r = blk - 96;
                const float* ERp = wsf + OFF_EREAD + (size_t)(t - 1) * 32768;
                const float* ROp = wsf + OFF_RO;
#pragma unroll
                for (int i = 0; i < 8; ++i) {
                    const int e = (r << 11) + (i << 8) + tid;
                    const int b = e >> 8, j2 = e & 255;
                    const int bi = b * 512 + (j2 << 1);
                    float v0 = ERp[bi] + ROp[bi] + ROp[32768 + bi] + ROp[65536 + bi] + ROp[98304 + bi];
                    float v1 = ERp[bi + 1] + ROp[bi + 1] + ROp[32768 + bi + 1] + ROp[65536 + bi + 1] + ROp[98304 + bi + 1];
                    dout[OO_G + (size_t)(t - 1) * 16384 + b * 256 + j2] = fmaxf(v0, v1);
                }
            }
        }
        gbar(cnt, gen, g);

        // ---- Phase D: per-b attention (blocks 0-63) ----
        if (blk < 64) {
            const int b = blk;
            float* s_out = lds_x;            // 512
            float* s_q   = lds_x + 512;      // 512
            float* s_e   = lds_x + 1024;     // 128
            float* s_at  = lds_x + 1152;     // 128
            float* s_ctx = lds_x + 1280;     // 512
            float* s_red = lds_x + 1792;     // 256
            const float* GI1p = wsf + OFF_GI1;
            const float* GH1p = wsf + OFF_GH1;
            // combine out = GRU1(h0_cur, h1_prv) gate outputs
            for (int c = tid; c < 512; c += 256) {
                const int base = b * 1536 + c;
                float ir = GI1p[base] + GI1p[98304 + base] + GI1p[196608 + base] + GI1p[294912 + base];
                float iz = GI1p[base + 512] + GI1p[98304 + base + 512] + GI1p[196608 + base + 512] + GI1p[294912 + base + 512];
                float in_ = GI1p[base + 1024] + GI1p[98304 + base + 1024] + GI1p[196608 + base + 1024] + GI1p[294912 + base + 1024];
                float hr = GH1p[base] + GH1p[98304 + base];
                float hz = GH1p[base + 512] + GH1p[98304 + base + 512];
                float hn = GH1p[base + 1024] + GH1p[98304 + base + 1024];
                float rr = sigm(ir + hr);
                float zz = sigm(iz + hz);
                float nn = tanh_(in_ + rr * hn);
                float o = (1.f - zz) * nn + zz * h1_prv[b * 512 + c];
                s_out[c] = o;
                h1_cur[b * 512 + c] = o;
            }
            __syncthreads();
            // q = out @ W_q^T (transposed weight for coalesced access)
            {
                const float* WTQ = wsf + OFF_WTQ;
                float q0 = 0.f, q1 = 0.f;
#pragma unroll 8
                for (int k = 0; k < 512; ++k) {
                    float ov = s_out[k];
                    q0 = fmaf(ov, WTQ[k * 512 + tid], q0);
                    q1 = fmaf(ov, WTQ[k * 512 + tid + 256], q1);
                }
                s_q[tid] = q0; s_q[tid + 256] = q1;
            }
            __syncthreads();
            // energy[s] = sum_a tanh(pre + q) * w_v ; one wave per s
            {
                const int wid = tid >> 6, lane = tid & 63;
                for (int s = wid; s < 128; s += 4) {
                    const float* pre = wsf + OFF_ATTPRE + ((size_t)b * 128 + s) * 512;
                    float acc = 0.f;
#pragma unroll
                    for (int i = 0; i < 8; ++i) {
                        const int a = lane + (i << 6);
                        acc += tanh_(pre[a] + s_q[a]) * w_v[a];
                    }
#pragma unroll
                    for (int d2 = 1; d2 < 64; d2 <<= 1) acc += __shfl_xor(acc, d2, 64);
                    if (lane == 0)
                        s_e[s] = (maskp[b * 128 + s] > 0.5f) ? -3.0e38f : acc;
                }
            }
            __syncthreads();
            // softmax over S=128 (wave 0)
            if (tid < 64) {
                float e0 = s_e[tid], e1 = s_e[tid + 64];
                float mx = fmaxf(e0, e1);
#pragma unroll
                for (int d2 = 1; d2 < 64; d2 <<= 1) mx = fmaxf(mx, __shfl_xor(mx, d2, 64));
                float x0 = __expf(e0 - mx), x1 = __expf(e1 - mx);
                float sm = x0 + x1;
#pragma unroll
                for (int d2 = 1; d2 < 64; d2 <<= 1) sm += __shfl_xor(sm, d2, 64);
                float inv = 1.f / sm;
                x0 *= inv; x1 *= inv;
                s_at[tid] = x0; s_at[tid + 64] = x1;
                float* co = dout + OO_C + ((size_t)t * 64 + b) * 128;
                co[tid] = x0; co[tid + 64] = x1;
                if (t == 31) {
                    dout[OO_AL + b * 128 + tid] = x0;
                    dout[OO_AL + b * 128 + tid + 64] = x1;
                }
            }
            __syncthreads();
            // new_ctx = attn @ ctx_bse
            for (int e = tid; e < 512; e += 256) {
                float acc = 0.f;
                for (int s = 0; s < 128; ++s)
                    acc = fmaf(s_at[s], ctxin[((size_t)s * 64 + b) * 512 + e], acc);
                s_ctx[e] = acc;
                ctx_cur[b * 512 + e] = acc;
            }
            __syncthreads();
            // copy gate
            {
                float part = 0.f;
                for (int i2 = tid; i2 < 512; i2 += 256)
                    part += s_out[i2] * W_copy[i2] + s_ctx[i2] * W_copy[512 + i2];
                s_red[tid] = part;
                __syncthreads();
                for (int d2 = 128; d2 > 0; d2 >>= 1) {
                    if (tid < d2) s_red[tid] += s_red[tid + d2];
                    __syncthreads();
                }
                if (tid == 0)
                    dout[OO_CP + t * 64 + b] = sigm(s_red[0] + b_copy[0]);
            }
        }
        gbar(cnt, gen, g);
    }

    // ===================== EPILOGUE =====================
    // readout GEMM for t=31 (final buffers are index 1) + state outputs
    if (blk < 32) {
        const int r = blk, mat = r >> 4, kh = (r >> 3) & 1, jt = r & 7, j0 = jt << 6;
        const float* X = mat ? (wsf + OFF_CTX + 32768) : (wsf + OFF_H1 + 32768);
        gemm64(X + rl * 512,
               W_read + (size_t)(j0 + rl) * 1536 + 512 + mat * 512,
               kh * 4, 4, lds_x, lds_w,
               wsf + OFF_RO + (mat * 2 + kh) * 32768, 512, 0, j0, nullptr, 0, 0);
    } else if (blk < 34) {
        const int base = (blk - 32) * 16384;
        for (int i = 0; i < 64; ++i) { int e = base + i * 256 + tid; dout[OO_HID + e] = wsf[OFF_H0 + 32768 + e]; }
    } else if (blk < 36) {
        const int base = (blk - 34) * 16384;
        for (int i = 0; i < 64; ++i) { int e = base + i * 256 + tid; dout[OO_HID + 32768 + e] = wsf[OFF_H1 + 32768 + e]; }
    } else if (blk < 38) {
        const int base = (blk - 36) * 16384;
        for (int i = 0; i < 64; ++i) { int e = base + i * 256 + tid; dout[OO_CTXF + e] = wsf[OFF_CTX + 32768 + e]; }
    }
    gbar(cnt, gen, g);
    // maxout for t=31
    if (blk < 8) {
        const float* ERp = wsf + OFF_EREAD + (size_t)31 * 32768;
        const float* ROp = wsf + OFF_RO;
        for (int i = 0; i < 8; ++i) {
            const int e = (blk << 11) + (i << 8) + tid;
            const int b = e >> 8, j2 = e & 255;
            const int bi = b * 512 + (j2 << 1);
            float v0 = ERp[bi] + ROp[bi] + ROp[32768 + bi] + ROp[65536 + bi] + ROp[98304 + bi];
            float v1 = ERp[bi + 1] + ROp[bi + 1] + ROp[32768 + bi + 1] + ROp[65536 + bi + 1] + ROp[98304 + bi + 1];
            dout[OO_G + (size_t)31 * 16384 + b * 256 + j2] = fmaxf(v0, v1);
        }
    }
}

extern "C" void kernel_launch(void* const* d_in, const int* in_sizes, int n_in,
                              void* d_out, int out_size, void* d_ws, size_t ws_size,
                              hipStream_t stream) {
    // zero the grid-barrier state (counter + generation) every call
    hipMemsetAsync(d_ws, 0, 256, stream);
    decoder_kernel<<<dim3(NBLK), dim3(NTHR), 0, stream>>>(
        (const int*)d_in[0],   (const float*)d_in[1],  (const float*)d_in[2],
        (const float*)d_in[3], (const float*)d_in[4],  (const float*)d_in[5],
        (const float*)d_in[6], (const float*)d_in[7],  (const float*)d_in[8],
        (const float*)d_in[9], (const float*)d_in[10], (const float*)d_in[11],
        (const float*)d_in[12],(const float*)d_in[13], (const float*)d_in[14],
        (const float*)d_in[15],(const float*)d_in[16], (const float*)d_in[17],
        (const float*)d_in[18],(const float*)d_in[19], (const float*)d_in[20],
        (const float*)d_in[21],
        (float*)d_out, (float*)d_ws);
}

// Round 2
// 3134.321 us; speedup vs baseline: 3.9030x; 3.9030x over previous
//
#include <hip/hip_runtime.h>

// ---------------------------------------------------------------------------
// GRU decoder w/ attention. Round 2: graph-of-kernels (5 dispatches/step).
// Round-1 post-mortem: persistent kernel's agent-fence grid barrier caused
// 256 blocks x 128 barriers of L2 writeback/invalidate -> 12.2ms, VALUBusy 3%.
// Dispatch boundaries provide cross-XCD coherence once per phase instead.
// ---------------------------------------------------------------------------

// ---- workspace layout (float offsets), total 39.06 MB ----
#define OFF_EGI    0          // [t*64+b][1536] emb part of gi0 (+b_ih0)
#define OFF_EREAD  3145728    // [t*64+b][512] emb part of readout (+b_read)
#define OFF_ATTPRE 4194304    // [b*128+s][512] attn precompute (+b_pre)
#define OFF_Q      8388608    // 4 k-split partials [64][512]
#define OFF_GI     8454144    // 4 partials [64][1536] (part0 includes Egi)
#define OFF_GH     8847360    // 4 partials (aliased by GI1 after consumption)
#define OFF_GI1    8847360    // alias of OFF_GH (GH consumed in k_h0, GI1 written in k_gi1)
#define OFF_GH1    9240576    // 2 partials
#define OFF_RO     9437184    // 4 partials [64][512]
#define OFF_H0     9568256    // double buffered [2][64][512]
#define OFF_H1     9633792
#define OFF_CTX    9699328

// ---- output layout (float offsets into d_out) ----
#define OO_G    0            // g_outputs [32][64][256]
#define OO_C    524288       // c_outputs [32][64][128]
#define OO_CP   786432       // copy_gates [32][64][1]
#define OO_HID  788480       // hidden_f [2][64][512]
#define OO_AL   854016       // attn_last [64][128]
#define OO_CTXF 862208       // cur_ctx_f [64][512]

__device__ __forceinline__ float sigm(float x) {
    x = fminf(fmaxf(x, -30.f), 30.f);
    return 1.0f / (1.0f + __expf(-x));
}
__device__ __forceinline__ float tanh_(float x) {
    x = fminf(fmaxf(x, -15.f), 15.f);
    float e = __expf(-2.0f * x);
    return (1.0f - e) / (1.0f + e);
}
__device__ __forceinline__ float gru_out(float ir, float iz, float in_,
                                         float hr, float hz, float hn, float hp) {
    float r = sigm(ir + hr), z = sigm(iz + hz);
    float n = tanh_(in_ + r * hn);
    return (1.f - z) * n + z * hp;
}

// Tiled GEMM: OUT[64 x 64tile] (+=addp) = X[64 x K] @ W[j][k]^T, K-tiles
// [kt0, kt0+nkt). xrow/wrow = this thread's staging row pointers (row=tid>>2).
// LDS tiles stored transposed ([k][row]) -> conflict-free inner reads.
__device__ __forceinline__ void gemm64(
    const float* __restrict__ xrow, const float* __restrict__ wrow,
    int kt0, int nkt, float* lds_x, float* lds_w,
    float* __restrict__ outp, int JW, int orow0, int j0,
    const float* __restrict__ addp, int addmode, int addJW)
{
    const int tid = threadIdx.x;
    const int tb4 = tid >> 4, tj4 = tid & 15;
    float acc[4][4];
#pragma unroll
    for (int a = 0; a < 4; ++a)
#pragma unroll
        for (int b = 0; b < 4; ++b) acc[a][b] = 0.f;

    for (int kt = kt0; kt < kt0 + nkt; ++kt) {
        const int kb = kt << 6;
        __syncthreads();
        {
            const int rl = tid >> 2;
#pragma unroll
            for (int i = 0; i < 4; ++i) {
                const int kk = ((tid & 3) << 4) + (i << 2);
                float4 xv = *(const float4*)(xrow + kb + kk);
                float4 wv = *(const float4*)(wrow + kb + kk);
                lds_x[(kk + 0) * 64 + rl] = xv.x;
                lds_x[(kk + 1) * 64 + rl] = xv.y;
                lds_x[(kk + 2) * 64 + rl] = xv.z;
                lds_x[(kk + 3) * 64 + rl] = xv.w;
                lds_w[(kk + 0) * 64 + rl] = wv.x;
                lds_w[(kk + 1) * 64 + rl] = wv.y;
                lds_w[(kk + 2) * 64 + rl] = wv.z;
                lds_w[(kk + 3) * 64 + rl] = wv.w;
            }
        }
        __syncthreads();
#pragma unroll 4
        for (int kk = 0; kk < 64; ++kk) {
            float4 xv = *(const float4*)(lds_x + kk * 64 + tb4 * 4);
            float4 wv = *(const float4*)(lds_w + kk * 64 + tj4 * 4);
            acc[0][0] += xv.x * wv.x; acc[0][1] += xv.x * wv.y;
            acc[0][2] += xv.x * wv.z; acc[0][3] += xv.x * wv.w;
            acc[1][0] += xv.y * wv.x; acc[1][1] += xv.y * wv.y;
            acc[1][2] += xv.y * wv.z; acc[1][3] += xv.y * wv.w;
            acc[2][0] += xv.z * wv.x; acc[2][1] += xv.z * wv.y;
            acc[2][2] += xv.z * wv.z; acc[2][3] += xv.z * wv.w;
            acc[3][0] += xv.w * wv.x; acc[3][1] += xv.w * wv.y;
            acc[3][2] += xv.w * wv.z; acc[3][3] += xv.w * wv.w;
        }
    }
#pragma unroll
    for (int ib = 0; ib < 4; ++ib) {
        const int row = tb4 * 4 + ib;
        const int jc = j0 + tj4 * 4;
        float4 r;
        r.x = acc[ib][0]; r.y = acc[ib][1]; r.z = acc[ib][2]; r.w = acc[ib][3];
        if (addmode == 1) {
            float4 bv = *(const float4*)(addp + jc);
            r.x += bv.x; r.y += bv.y; r.z += bv.z; r.w += bv.w;
        } else if (addmode == 2) {
            float4 bv = *(const float4*)(addp + (size_t)(orow0 + row) * addJW + jc);
            r.x += bv.x; r.y += bv.y; r.z += bv.z; r.w += bv.w;
        }
        *(float4*)(outp + (size_t)(orow0 + row) * JW + jc) = r;
    }
}

// =================== upfront: Egi, Eread, attpre, state init ===============
__global__ __launch_bounds__(256)
void k_upfront(const int* __restrict__ inp, const float* __restrict__ hid,
               const float* __restrict__ ctxin, const float* __restrict__ init_att,
               const float* __restrict__ embW,
               const float* __restrict__ W_ih0, const float* __restrict__ b_ih0,
               const float* __restrict__ W_read, const float* __restrict__ b_read,
               const float* __restrict__ W_pre, const float* __restrict__ b_pre,
               float* __restrict__ wsf)
{
    __shared__ float lds_x[4096], lds_w[4096];
    const int jid = blockIdx.x, tid = threadIdx.x, rl = tid >> 2;
    if (jid < 768) {
        const int mt = jid / 24, jt = jid % 24, j0 = jt << 6;
        const int idx = inp[mt * 64 + rl];
        gemm64(embW + (size_t)idx * 512, W_ih0 + (size_t)(j0 + rl) * 1024,
               0, 8, lds_x, lds_w, wsf + OFF_EGI, 1536, mt << 6, j0, b_ih0, 1, 0);
    } else if (jid < 1024) {
        const int r = jid - 768, mt = r >> 3, jt = r & 7, j0 = jt << 6;
        const int idx = inp[mt * 64 + rl];
        gemm64(embW + (size_t)idx * 512, W_read + (size_t)(j0 + rl) * 1536,
               0, 8, lds_x, lds_w, wsf + OFF_EREAD, 512, mt << 6, j0, b_read, 1, 0);
    } else if (jid < 2048) {
        const int r = jid - 1024, mt = r >> 3, jt = r & 7, j0 = jt << 6;
        const int m = (mt << 6) + rl, b = m >> 7, s = m & 127;
        gemm64(ctxin + (size_t)((s << 6) + b) * 512, W_pre + (size_t)(j0 + rl) * 512,
               0, 8, lds_x, lds_w, wsf + OFF_ATTPRE, 512, mt << 6, j0, b_pre, 1, 0);
    } else {
        const int job = jid - 2048, buf = job >> 1, half = job & 1;
        const float* src = buf == 0 ? hid : (buf == 1 ? hid + 32768 : init_att);
        float* dst = wsf + (buf == 0 ? OFF_H0 : (buf == 1 ? OFF_H1 : OFF_CTX)) + 32768;
        for (int i = 0; i < 64; ++i) {
            int e = half * 16384 + i * 256 + tid;
            dst[e] = src[e];
        }
    }
}

// =================== K1: gate GEMMs + readout(t-1) ===================
__global__ __launch_bounds__(256)
void k_gates(int t, const float* __restrict__ W_ih0,
             const float* __restrict__ W_hh0, const float* __restrict__ b_hh0,
             const float* __restrict__ W_hh1, const float* __restrict__ b_hh1,
             const float* __restrict__ W_read, float* __restrict__ wsf)
{
    __shared__ float lds_x[4096], lds_w[4096];
    const int blk = blockIdx.x, tid = threadIdx.x, rl = tid >> 2;
    const int prv = (t & 1) ^ 1;
    const float* ctx_prv = wsf + OFF_CTX + prv * 32768;
    const float* h0_prv  = wsf + OFF_H0 + prv * 32768;
    const float* h1_prv  = wsf + OFF_H1 + prv * 32768;
    if (blk < 96) {
        const int jt = blk >> 2, kq = blk & 3, j0 = jt << 6;
        gemm64(ctx_prv + rl * 512, W_ih0 + (size_t)(j0 + rl) * 1024 + 512,
               kq * 2, 2, lds_x, lds_w, wsf + OFF_GI + kq * 98304, 1536, 0, j0,
               wsf + OFF_EGI + (size_t)t * 98304, kq == 0 ? 2 : 0, 1536);
    } else if (blk < 192) {
        const int r = blk - 96, jt = r >> 2, kq = r & 3, j0 = jt << 6;
        gemm64(h0_prv + rl * 512, W_hh0 + (size_t)(j0 + rl) * 512,
               kq * 2, 2, lds_x, lds_w, wsf + OFF_GH + kq * 98304, 1536, 0, j0,
               b_hh0, kq == 0 ? 1 : 0, 0);
    } else if (blk < 240) {
        const int r = blk - 192, jt = r >> 1, kh = r & 1, j0 = jt << 6;
        gemm64(h1_prv + rl * 512, W_hh1 + (size_t)(j0 + rl) * 512,
               kh * 4, 4, lds_x, lds_w, wsf + OFF_GH1 + kh * 98304, 1536, 0, j0,
               b_hh1, kh == 0 ? 1 : 0, 0);
    } else {
        if (t == 0) return;   // no readout before step 0
        const int r = blk - 240, mat = r >> 4, kh = (r >> 3) & 1, jt = r & 7, j0 = jt << 6;
        const float* X = mat ? ctx_prv : h1_prv;   // out_{t-1} = h1_prv
        gemm64(X + rl * 512, W_read + (size_t)(j0 + rl) * 1536 + 512 + mat * 512,
               kh * 4, 4, lds_x, lds_w, wsf + OFF_RO + (mat * 2 + kh) * 32768, 512, 0, j0,
               nullptr, 0, 0);
    }
}

// =================== K2: h0 combine + maxout(t-1) ===================
__global__ __launch_bounds__(256)
void k_h0(int t, float* __restrict__ wsf, float* __restrict__ dout)
{
    const int blk = blockIdx.x, tid = threadIdx.x;
    const int cur = t & 1, prv = cur ^ 1;
    if (blk < 16) {
        float* h0_cur = wsf + OFF_H0 + cur * 32768;
        const float* h0_prv = wsf + OFF_H0 + prv * 32768;
        const float* GIp = wsf + OFF_GI;
        const float* GHp = wsf + OFF_GH;
#pragma unroll
        for (int i = 0; i < 8; ++i) {
            const int e = (blk << 11) + (i << 8) + tid;
            const int b = e >> 9, c = e & 511;
            const int base = b * 1536 + c;
            float gr = 0, gz = 0, gn = 0, hr = 0, hz = 0, hn = 0;
#pragma unroll
            for (int p = 0; p < 4; ++p) {
                gr += GIp[p * 98304 + base];
                gz += GIp[p * 98304 + base + 512];
                gn += GIp[p * 98304 + base + 1024];
                hr += GHp[p * 98304 + base];
                hz += GHp[p * 98304 + base + 512];
                hn += GHp[p * 98304 + base + 1024];
            }
            float rr = sigm(gr + hr), zz = sigm(gz + hz);
            float nn = tanh_(gn + rr * hn);
            h0_cur[b * 512 + c] = (1.f - zz) * nn + zz * h0_prv[b * 512 + c];
        }
    } else {
        if (t == 0) return;
        const int r = blk - 16;
        const float* ERp = wsf + OFF_EREAD + (size_t)(t - 1) * 32768;
        const float* ROp = wsf + OFF_RO;
#pragma unroll
        for (int i = 0; i < 8; ++i) {
            const int e = (r << 11) + (i << 8) + tid;
            const int b = e >> 8, j2 = e & 255;
            const int bi = b * 512 + (j2 << 1);
            float v0 = ERp[bi] + ROp[bi] + ROp[32768 + bi] + ROp[65536 + bi] + ROp[98304 + bi];
            float v1 = ERp[bi + 1] + ROp[bi + 1] + ROp[32768 + bi + 1] + ROp[65536 + bi + 1] + ROp[98304 + bi + 1];
            dout[OO_G + (size_t)(t - 1) * 16384 + b * 256 + j2] = fmaxf(v0, v1);
        }
    }
}

// =================== K3: gi1 GEMM ===================
__global__ __launch_bounds__(256)
void k_gi1(int t, const float* __restrict__ W_ih1, const float* __restrict__ b_ih1,
           float* __restrict__ wsf)
{
    __shared__ float lds_x[4096], lds_w[4096];
    const int blk = blockIdx.x, tid = threadIdx.x, rl = tid >> 2;
    const int cur = t & 1;
    const float* h0_cur = wsf + OFF_H0 + cur * 32768;
    const int jt = blk >> 2, kq = blk & 3, j0 = jt << 6;
    gemm64(h0_cur + rl * 512, W_ih1 + (size_t)(j0 + rl) * 512,
           kq * 2, 2, lds_x, lds_w, wsf + OFF_GI1 + kq * 98304, 1536, 0, j0,
           b_ih1, kq == 0 ? 1 : 0, 0);
}

// =================== K4: out combine (per k-slice, redundant) + q GEMM =======
// 32 blocks: jt in [0,8) (a-col tile), kq in [0,4) (128-wide k slice).
// Each block recombines out[:, kq-slice] from gi1/gh1 partials (1.1 MB L2/LLC
// read), stages it in LDS, multiplies by W_q rows. jt==0 blocks also publish
// h1_cur slice for K5 / next step.
__global__ __launch_bounds__(256)
void k_oq(int t, const float* __restrict__ W_q, float* __restrict__ wsf)
{
    __shared__ float s_o[64 * 129];   // out slice, row-major [b][k], pad 129
    __shared__ float s_w[64 * 64];    // W_q tile, transposed [k][a]
    const int blk = blockIdx.x, tid = threadIdx.x;
    const int cur = t & 1, prv = cur ^ 1;
    const float* GI1p = wsf + OFF_GI1;
    const float* GH1p = wsf + OFF_GH1;
    const float* h1_prv = wsf + OFF_H1 + prv * 32768;
    float* h1_cur = wsf + OFF_H1 + cur * 32768;
    const int jt = blk >> 2, kq = blk & 3, j0 = jt << 6;
    const int kbase = kq << 7;
    const int tb4 = tid >> 4, tj4 = tid & 15, rl = tid >> 2;

    // ---- combine out[:, kbase..kbase+128) ----
#pragma unroll
    for (int i = 0; i < 8; ++i) {
        const int f = (i << 8) + tid;
        const int b = f >> 5, c4 = f & 31;
        const int c = kbase + (c4 << 2);
        float4 ir = {0,0,0,0}, iz = ir, in4 = ir, hr = ir, hz = ir, hn = ir;
#pragma unroll
        for (int p = 0; p < 4; ++p) {
            const float* gp = GI1p + p * 98304 + b * 1536 + c;
            float4 a0 = *(const float4*)(gp);
            float4 a1 = *(const float4*)(gp + 512);
            float4 a2 = *(const float4*)(gp + 1024);
            ir.x += a0.x; ir.y += a0.y; ir.z += a0.z; ir.w += a0.w;
            iz.x += a1.x; iz.y += a1.y; iz.z += a1.z; iz.w += a1.w;
            in4.x += a2.x; in4.y += a2.y; in4.z += a2.z; in4.w += a2.w;
        }
#pragma unroll
        for (int p = 0; p < 2; ++p) {
            const float* gp = GH1p + p * 98304 + b * 1536 + c;
            float4 a0 = *(const float4*)(gp);
            float4 a1 = *(const float4*)(gp + 512);
            float4 a2 = *(const float4*)(gp + 1024);
            hr.x += a0.x; hr.y += a0.y; hr.z += a0.z; hr.w += a0.w;
            hz.x += a1.x; hz.y += a1.y; hz.z += a1.z; hz.w += a1.w;
            hn.x += a2.x; hn.y += a2.y; hn.z += a2.z; hn.w += a2.w;
        }
        float4 hp = *(const float4*)(h1_prv + b * 512 + c);
        float4 o;
        o.x = gru_out(ir.x, iz.x, in4.x, hr.x, hz.x, hn.x, hp.x);
        o.y = gru_out(ir.y, iz.y, in4.y, hr.y, hz.y, hn.y, hp.y);
        o.z = gru_out(ir.z, iz.z, in4.z, hr.z, hz.z, hn.z, hp.z);
        o.w = gru_out(ir.w, iz.w, in4.w, hr.w, hz.w, hn.w, hp.w);
        const int kl = c4 << 2;
        s_o[b * 129 + kl + 0] = o.x;
        s_o[b * 129 + kl + 1] = o.y;
        s_o[b * 129 + kl + 2] = o.z;
        s_o[b * 129 + kl + 3] = o.w;
        if (jt == 0) *(float4*)(h1_cur + b * 512 + c) = o;
    }

    // ---- q partial = out_slice @ W_q[j-tile]^T ----
    float acc[4][4];
#pragma unroll
    for (int a = 0; a < 4; ++a)
#pragma unroll
        for (int b = 0; b < 4; ++b) acc[a][b] = 0.f;

    for (int kt = 0; kt < 2; ++kt) {
        __syncthreads();   // also covers combine->gemm for kt==0
        {
            const float* wrow = W_q + (size_t)(j0 + rl) * 512 + kbase + kt * 64;
#pragma unroll
            for (int i = 0; i < 4; ++i) {
                const int kk = ((tid & 3) << 4) + (i << 2);
                float4 wv = *(const float4*)(wrow + kk);
                s_w[(kk + 0) * 64 + rl] = wv.x;
                s_w[(kk + 1) * 64 + rl] = wv.y;
                s_w[(kk + 2) * 64 + rl] = wv.z;
                s_w[(kk + 3) * 64 + rl] = wv.w;
            }
        }
        __syncthreads();
#pragma unroll 4
        for (int kk = 0; kk < 64; ++kk) {
            const int ka = kt * 64 + kk;
            float x0 = s_o[(tb4 * 4 + 0) * 129 + ka];
            float x1 = s_o[(tb4 * 4 + 1) * 129 + ka];
            float x2 = s_o[(tb4 * 4 + 2) * 129 + ka];
            float x3 = s_o[(tb4 * 4 + 3) * 129 + ka];
            float4 wv = *(const float4*)(s_w + kk * 64 + tj4 * 4);
            acc[0][0] += x0 * wv.x; acc[0][1] += x0 * wv.y; acc[0][2] += x0 * wv.z; acc[0][3] += x0 * wv.w;
            acc[1][0] += x1 * wv.x; acc[1][1] += x1 * wv.y; acc[1][2] += x1 * wv.z; acc[1][3] += x1 * wv.w;
            acc[2][0] += x2 * wv.x; acc[2][1] += x2 * wv.y; acc[2][2] += x2 * wv.z; acc[2][3] += x2 * wv.w;
            acc[3][0] += x3 * wv.x; acc[3][1] += x3 * wv.y; acc[3][2] += x3 * wv.z; acc[3][3] += x3 * wv.w;
        }
    }
    float* Qp = wsf + OFF_Q + kq * 32768;
#pragma unroll
    for (int ib = 0; ib < 4; ++ib) {
        float4 r;
        r.x = acc[ib][0]; r.y = acc[ib][1]; r.z = acc[ib][2]; r.w = acc[ib][3];
        *(float4*)(Qp + (size_t)(tb4 * 4 + ib) * 512 + j0 + tj4 * 4) = r;
    }
}

// =================== K5: per-b attention: energy/softmax/ctx/copy ==========
__global__ __launch_bounds__(256)
void k_att(int t, const float* __restrict__ ctxin, const float* __restrict__ maskp,
           const float* __restrict__ w_v, const float* __restrict__ W_copy,
           const float* __restrict__ b_copy, float* __restrict__ wsf,
           float* __restrict__ dout)
{
    __shared__ float s_q[512];
    __shared__ float s_e[128];
    __shared__ float s_at[128];
    __shared__ float s_ctx[512];
    __shared__ float s_red[256];
    const int b = blockIdx.x, tid = threadIdx.x;
    const int cur = t & 1;
    float* ctx_cur = wsf + OFF_CTX + cur * 32768;
    const float* h1_cur = wsf + OFF_H1 + cur * 32768;
    const float* Qp = wsf + OFF_Q;
    // q = sum of 4 k-split partials
#pragma unroll
    for (int h = 0; h < 2; ++h) {
        const int a = h * 256 + tid;
        s_q[a] = Qp[b * 512 + a] + Qp[32768 + b * 512 + a]
               + Qp[65536 + b * 512 + a] + Qp[98304 + b * 512 + a];
    }
    __syncthreads();
    // energy[s] = w_v . tanh(pre[b,s,:] + q)
    {
        const int wid = tid >> 6, lane = tid & 63;
        for (int s = wid; s < 128; s += 4) {
            const float* pre = wsf + OFF_ATTPRE + ((size_t)b * 128 + s) * 512;
            float acc = 0.f;
#pragma unroll
            for (int i = 0; i < 8; ++i) {
                const int a = lane + (i << 6);
                acc += tanh_(pre[a] + s_q[a]) * w_v[a];
            }
#pragma unroll
            for (int d2 = 1; d2 < 64; d2 <<= 1) acc += __shfl_xor(acc, d2, 64);
            if (lane == 0)
                s_e[s] = (maskp[b * 128 + s] > 0.5f) ? -3.0e38f : acc;
        }
    }
    __syncthreads();
    // softmax over S=128
    if (tid < 64) {
        float e0 = s_e[tid], e1 = s_e[tid + 64];
        float mx = fmaxf(e0, e1);
#pragma unroll
        for (int d2 = 1; d2 < 64; d2 <<= 1) mx = fmaxf(mx, __shfl_xor(mx, d2, 64));
        float x0 = __expf(e0 - mx), x1 = __expf(e1 - mx);
        float sm = x0 + x1;
#pragma unroll
        for (int d2 = 1; d2 < 64; d2 <<= 1) sm += __shfl_xor(sm, d2, 64);
        float inv = 1.f / sm;
        x0 *= inv; x1 *= inv;
        s_at[tid] = x0; s_at[tid + 64] = x1;
        float* co = dout + OO_C + ((size_t)t * 64 + b) * 128;
        co[tid] = x0; co[tid + 64] = x1;
        if (t == 31) {
            dout[OO_AL + b * 128 + tid] = x0;
            dout[OO_AL + b * 128 + tid + 64] = x1;
        }
    }
    __syncthreads();
    // new_ctx = attn @ ctx_bse
    for (int e = tid; e < 512; e += 256) {
        float acc = 0.f;
        for (int s = 0; s < 128; ++s)
            acc = fmaf(s_at[s], ctxin[((size_t)s * 64 + b) * 512 + e], acc);
        s_ctx[e] = acc;
        ctx_cur[b * 512 + e] = acc;
    }
    __syncthreads();
    // copy gate: sigmoid([out, ctx] @ W_copy^T + b_copy)
    {
        float part = 0.f;
        for (int i2 = tid; i2 < 512; i2 += 256)
            part += h1_cur[b * 512 + i2] * W_copy[i2] + s_ctx[i2] * W_copy[512 + i2];
        s_red[tid] = part;
        __syncthreads();
        for (int d2 = 128; d2 > 0; d2 >>= 1) {
            if (tid < d2) s_red[tid] += s_red[tid + d2];
            __syncthreads();
        }
        if (tid == 0)
            dout[OO_CP + t * 64 + b] = sigm(s_red[0] + b_copy[0]);
    }
}

// =================== epilogue ===================
__global__ __launch_bounds__(256)
void k_epi1(const float* __restrict__ W_read, float* __restrict__ wsf,
            float* __restrict__ dout)
{
    __shared__ float lds_x[4096], lds_w[4096];
    const int blk = blockIdx.x, tid = threadIdx.x, rl = tid >> 2;
    if (blk < 32) {   // readout GEMM for t=31 (final buffers at index 1)
        const int mat = blk >> 4, kh = (blk >> 3) & 1, jt = blk & 7, j0 = jt << 6;
        const float* X = mat ? (wsf + OFF_CTX + 32768) : (wsf + OFF_H1 + 32768);
        gemm64(X + rl * 512, W_read + (size_t)(j0 + rl) * 1536 + 512 + mat * 512,
               kh * 4, 4, lds_x, lds_w, wsf + OFF_RO + (mat * 2 + kh) * 32768, 512, 0, j0,
               nullptr, 0, 0);
    } else if (blk < 34) {
        const int base = (blk - 32) * 16384;
        for (int i = 0; i < 64; ++i) { int e = base + i * 256 + tid; dout[OO_HID + e] = wsf[OFF_H0 + 32768 + e]; }
    } else if (blk < 36) {
        const int base = (blk - 34) * 16384;
        for (int i = 0; i < 64; ++i) { int e = base + i * 256 + tid; dout[OO_HID + 32768 + e] = wsf[OFF_H1 + 32768 + e]; }
    } else {
        const int base = (blk - 36) * 16384;
        for (int i = 0; i < 64; ++i) { int e = base + i * 256 + tid; dout[OO_CTXF + e] = wsf[OFF_CTX + 32768 + e]; }
    }
}

__global__ __launch_bounds__(256)
void k_epi2(float* __restrict__ wsf, float* __restrict__ dout)
{
    const int blk = blockIdx.x, tid = threadIdx.x;
    const float* ERp = wsf + OFF_EREAD + (size_t)31 * 32768;
    const float* ROp = wsf + OFF_RO;
#pragma unroll
    for (int i = 0; i < 8; ++i) {
        const int e = (blk << 11) + (i << 8) + tid;
        const int b = e >> 8, j2 = e & 255;
        const int bi = b * 512 + (j2 << 1);
        float v0 = ERp[bi] + ROp[bi] + ROp[32768 + bi] + ROp[65536 + bi] + ROp[98304 + bi];
        float v1 = ERp[bi + 1] + ROp[bi + 1] + ROp[32768 + bi + 1] + ROp[65536 + bi + 1] + ROp[98304 + bi + 1];
        dout[OO_G + (size_t)31 * 16384 + b * 256 + j2] = fmaxf(v0, v1);
    }
}

extern "C" void kernel_launch(void* const* d_in, const int* in_sizes, int n_in,
                              void* d_out, int out_size, void* d_ws, size_t ws_size,
                              hipStream_t stream) {
    const int*   inp      = (const int*)d_in[0];
    const float* hid      = (const float*)d_in[1];
    const float* ctxin    = (const float*)d_in[2];
    const float* maskp    = (const float*)d_in[3];
    const float* init_att = (const float*)d_in[4];
    const float* embW     = (const float*)d_in[5];
    const float* W_ih0    = (const float*)d_in[6];
    const float* b_ih0    = (const float*)d_in[7];
    const float* W_hh0    = (const float*)d_in[8];
    const float* b_hh0    = (const float*)d_in[9];
    const float* W_ih1    = (const float*)d_in[10];
    const float* b_ih1    = (const float*)d_in[11];
    const float* W_hh1    = (const float*)d_in[12];
    const float* b_hh1    = (const float*)d_in[13];
    const float* W_pre    = (const float*)d_in[14];
    const float* b_pre    = (const float*)d_in[15];
    const float* W_q      = (const float*)d_in[16];
    const float* w_v      = (const float*)d_in[17];
    const float* W_copy   = (const float*)d_in[18];
    const float* b_copy   = (const float*)d_in[19];
    const float* W_read   = (const float*)d_in[20];
    const float* b_read   = (const float*)d_in[21];
    float* dout = (float*)d_out;
    float* wsf  = (float*)d_ws;

    k_upfront<<<dim3(2054), dim3(256), 0, stream>>>(
        inp, hid, ctxin, init_att, embW, W_ih0, b_ih0, W_read, b_read, W_pre, b_pre, wsf);

    for (int t = 0; t < 32; ++t) {
        k_gates<<<dim3(272), dim3(256), 0, stream>>>(t, W_ih0, W_hh0, b_hh0, W_hh1, b_hh1, W_read, wsf);
        k_h0<<<dim3(24), dim3(256), 0, stream>>>(t, wsf, dout);
        k_gi1<<<dim3(96), dim3(256), 0, stream>>>(t, W_ih1, b_ih1, wsf);
        k_oq<<<dim3(32), dim3(256), 0, stream>>>(t, W_q, wsf);
        k_att<<<dim3(64), dim3(256), 0, stream>>>(t, ctxin, maskp, w_v, W_copy, b_copy, wsf, dout);
    }
    k_epi1<<<dim3(38), dim3(256), 0, stream>>>(W_read, wsf, dout);
    k_epi2<<<dim3(8), dim3(256), 0, stream>>>(wsf, dout);
}